// Round 11
// baseline (489.205 us; speedup 1.0000x reference)
//
#include <hip/hip_runtime.h>
#include <hip/hip_bf16.h>
#include <hip/hip_fp8.h>

#define N_NODES 100000
#define N_EDGES 1600000
#define N_FEAT 7
#define HID 128
#define N_CLASS 5
#define N_GRAPHS 8
#define NPB 16  // nodes per block in fused layer kernels (grid 6250, 4 waves x 4 nodes)
#define SCAN_NBLK ((N_NODES + 1023) / 1024)   // 98
#define TLP 136  // padded LDS row (bf16 elems): 272 B stride
#define TLP1 40  // layer-1 padded LDS row (K=32 zero-padded + 8)
#define NBKT 98        // ceil(N_NODES / 1024) dst-buckets for local scatter
#define BKT_SHIFT 10
#define TILE 4096      // edges per partition block
#define CPB 16         // chunks per bucket in scatter_local

typedef __hip_bfloat16 bf16;
typedef __attribute__((ext_vector_type(8))) short short8;   // 8 bf16 (4 VGPRs)
typedef __attribute__((ext_vector_type(4))) float f32x4;    // MFMA accumulator

// fp8 e4m3 (OCP) helpers: gather payload compression.
// v7 theory: gather is fabric-bound (FETCH 192 MB pinned across r7/r9/r10 while
// VALU<=52%, occ 62%). Random graph -> no locality fix exists; only lever left
// is bytes/edge: 256 B bf16 row -> 128 B fp8 row, and working set 25.6->12.8 MB
// (vs 4 MB L2/XCD) so miss rate drops too.
__device__ __forceinline__ float dec8(unsigned v, int b) {
    __hip_fp8_e4m3 q;
    q.__x = (__hip_fp8_storage_t)((v >> (8 * b)) & 0xffu);
    return (float)q;
}
__device__ __forceinline__ unsigned char enc8(float v) {
    __hip_fp8_e4m3 q(v);
    return (unsigned char)q.__x;
}

// ---------------- CSR build (dst-sorted adjacency) ----------------

__global__ void hist_kernel(const int* __restrict__ dst, int* __restrict__ deg) {
    int e = blockIdx.x * blockDim.x + threadIdx.x;
    if (e < N_EDGES) atomicAdd(&deg[dst[e]], 1);
}

__global__ __launch_bounds__(1024) void scan_phase1(const int* __restrict__ deg,
                                                    int* __restrict__ tmp,
                                                    int* __restrict__ bsum) {
    __shared__ int s[1024];
    int tid = threadIdx.x;
    int i = blockIdx.x * 1024 + tid;
    int v = (i < N_NODES) ? deg[i] : 0;
    s[tid] = v;
    __syncthreads();
    for (int off = 1; off < 1024; off <<= 1) {
        int u = (tid >= off) ? s[tid - off] : 0;
        __syncthreads();
        s[tid] += u;
        __syncthreads();
    }
    if (i < N_NODES) tmp[i] = s[tid] - v;            // exclusive
    if (tid == 1023) bsum[blockIdx.x] = s[1023];
}

__global__ __launch_bounds__(128) void scan_phase2(int* __restrict__ bsum) {
    __shared__ int s[128];
    int tid = threadIdx.x;
    int v = (tid < SCAN_NBLK) ? bsum[tid] : 0;
    s[tid] = v;
    __syncthreads();
    for (int off = 1; off < 128; off <<= 1) {
        int u = (tid >= off) ? s[tid - off] : 0;
        __syncthreads();
        s[tid] += u;
        __syncthreads();
    }
    if (tid < SCAN_NBLK) bsum[tid] = s[tid] - v;
}

__global__ __launch_bounds__(1024) void scan_phase3(const int* __restrict__ tmp,
                                                    const int* __restrict__ bsum,
                                                    int* __restrict__ rowptr,
                                                    int* __restrict__ cursor,
                                                    int* __restrict__ bcur) {
    int i = blockIdx.x * 1024 + threadIdx.x;
    if (i < N_NODES) {
        int r = tmp[i] + bsum[blockIdx.x];
        rowptr[i] = r;
        cursor[i] = r;
        if ((i & 1023) == 0) bcur[i >> BKT_SHIFT] = r;   // bucket write cursors for partition
    }
    if (i == 0) rowptr[N_NODES] = N_EDGES;
}

// ---- Pass A: LDS counting-sort each edge tile by dst-bucket, write bucket-major ----
__global__ __launch_bounds__(256) void partition_kernel(
        const int* __restrict__ src, const int* __restrict__ dst,
        const float* __restrict__ ea, int* __restrict__ bcur,
        int2* __restrict__ tmp2, int* __restrict__ tmpd) {
    __shared__ int lsrc[TILE], lea[TILE], ldst[TILE];   // 48 KB
    __shared__ int cnt[NBKT], gbase[NBKT];
    __shared__ int off[128];
    int tid = threadIdx.x;
    int e0 = blockIdx.x * TILE;
    int nedge = N_EDGES - e0; if (nedge > TILE) nedge = TILE;

    for (int bkt = tid; bkt < NBKT; bkt += 256) cnt[bkt] = 0;
    __syncthreads();
    for (int t = tid; t < nedge; t += 256)
        atomicAdd(&cnt[dst[e0 + t] >> BKT_SHIFT], 1);
    __syncthreads();
    if (tid < 128) off[tid] = (tid < NBKT) ? cnt[tid] : 0;
    __syncthreads();
    for (int o = 1; o < 128; o <<= 1) {                  // Hillis-Steele inclusive scan
        int u = 0;
        if (tid < 128 && tid >= o) u = off[tid - o];
        __syncthreads();
        if (tid < 128) off[tid] += u;
        __syncthreads();
    }
    if (tid < NBKT) {
        off[tid] -= cnt[tid];                            // inclusive -> exclusive
        gbase[tid] = atomicAdd(&bcur[tid], cnt[tid]);    // reserve global bucket range
    }
    __syncthreads();
    if (tid < NBKT) cnt[tid] = 0;                        // reuse as rank counter
    __syncthreads();
    for (int t = tid; t < nedge; t += 256) {
        int d = dst[e0 + t];
        int bkt = d >> BKT_SHIFT;
        int sp = off[bkt] + atomicAdd(&cnt[bkt], 1);     // sorted slot in tile
        lsrc[sp] = src[e0 + t];
        lea[sp] = __float_as_int(ea[e0 + t]);
        ldst[sp] = d;
    }
    __syncthreads();
    for (int t = tid; t < nedge; t += 256) {             // bucket-grouped coalesced writeout
        int d = ldst[t];
        int bkt = d >> BKT_SHIFT;
        int gi = gbase[bkt] + (t - off[bkt]);
        tmp2[gi] = make_int2(lsrc[t], lea[t]);
        tmpd[gi] = d;
    }
}

// ---- Pass B: scatter within bucket, bucket pinned to one XCD (blockIdx%8) ----
__global__ __launch_bounds__(256) void scatter_local(
        const int2* __restrict__ tmp2, const int* __restrict__ tmpd,
        const int* __restrict__ rowptr, int* __restrict__ cursor,
        int2* __restrict__ csr) {
    int bid = blockIdx.x;
    int xcd = bid & 7;
    int grp = bid >> 3;
    int b = (grp / CPB) * 8 + xcd;       // bucket: all its chunks share blockIdx%8
    int c = grp % CPB;                    // chunk within bucket
    if (b >= NBKT) return;
    int r0 = rowptr[b << BKT_SHIFT];
    int nb1 = (b + 1) << BKT_SHIFT; if (nb1 > N_NODES) nb1 = N_NODES;
    int r1 = rowptr[nb1];
    int count = r1 - r0;
    int per = (count + CPB - 1) / CPB;
    int s = r0 + c * per;
    int e = s + per; if (e > r1) e = r1;
    for (int i = s + threadIdx.x; i < e; i += 256) {
        int d = tmpd[i];
        int p = atomicAdd(&cursor[d], 1);
        csr[p] = tmp2[i];
    }
}

// ---------------- W pre-pack into MFMA B-fragment order (bf16) ----------------
// B-frag for mfma_f32_16x16x32_bf16: lane l holds B[k=(l>>4)*8+q][col=l&15].

__global__ void pack_w(const float* __restrict__ W, bf16* __restrict__ Wp) {
    int t = blockIdx.x * blockDim.x + threadIdx.x;   // 0..2047
    if (t >= 2048) return;
    int l = t & 63;
    int kk = (t >> 6) & 3;
    int jt = t >> 8;
    int kbase = kk * 32 + (l >> 4) * 8;
    int j = jt * 16 + (l & 15);
#pragma unroll
    for (int q = 0; q < 8; ++q)
        Wp[t * 8 + q] = __float2bfloat16(W[(kbase + q) * HID + j]);
}

// Layer-1 W pack: K=7 zero-padded to 32. Wp1[(jt*64+l)*8+q] = W1[k][j] (k<7) else 0.
__global__ void pack_w1(const float* __restrict__ W, bf16* __restrict__ Wp) {
    int t = blockIdx.x * blockDim.x + threadIdx.x;   // 0..511
    if (t >= 512) return;
    int l = t & 63;
    int jt = t >> 6;
    int j = jt * 16 + (l & 15);
#pragma unroll
    for (int q = 0; q < 8; ++q) {
        int k = (l >> 4) * 8 + q;
        Wp[t * 8 + q] = __float2bfloat16(k < N_FEAT ? W[k * HID + j] : 0.f);
    }
}

// x pre-pack: fp32 [N][7] -> bf16 [N][8] (16 B rows, 1.6 MB: L2-resident).
__global__ void pack_x(const float* __restrict__ x, bf16* __restrict__ xp) {
    int n = blockIdx.x * blockDim.x + threadIdx.x;
    if (n >= N_NODES) return;
    unsigned short pk[8];
#pragma unroll
    for (int k = 0; k < N_FEAT; ++k) {
        bf16 h = __float2bfloat16(x[n * N_FEAT + k]);
        pk[k] = *(unsigned short*)&h;
    }
    pk[7] = 0;
    *(uint4*)&xp[(size_t)n * 8] = *(const uint4*)pk;
}

// ---------------- Fused layer 1: gather(xp, in=7) + MFMA; fp8 output ----------------
__global__ __launch_bounds__(256) void layer1_fused(
        const bf16* __restrict__ xp, const int2* __restrict__ csr,
        const int* __restrict__ rowptr, const float* __restrict__ We,
        const float* __restrict__ be, const bf16* __restrict__ Wp1,
        const float* __restrict__ b, unsigned char* __restrict__ hout8) {
    __shared__ __align__(16) unsigned short tl[NPB][TLP1];   // 1.28 KB
    int tid = threadIdx.x;
    int wave = tid >> 6;
    int lane = tid & 63;
    int sub = lane >> 4;
    int l = lane & 15;
    int n0 = blockIdx.x * NPB;

    for (int i = tid; i < NPB * TLP1; i += 256) ((unsigned short*)tl)[i] = 0;

    float we[N_FEAT], bee[N_FEAT], p[N_FEAT];
#pragma unroll
    for (int k = 0; k < N_FEAT; ++k) { we[k] = We[k]; bee[k] = be[k]; p[k] = 0.f; }
    __syncthreads();   // zero-init visible before lane-0 t-writes

    const uint4* xp4 = (const uint4*)xp;
    int m = wave * 4 + sub;
    int n = n0 + m;
    int r0 = rowptr[n], r1 = rowptr[n + 1];
    for (int i = r0 + l; i < r1; i += 16) {
        int2 sa = csr[i];
        float a = __int_as_float(sa.y);
        uint4 rv = xp4[sa.x];                        // whole 7-feat row, one load
#pragma unroll
        for (int p_ = 0; p_ < 4; ++p_) {
            unsigned u = ((const unsigned*)&rv)[p_];
            float f0 = __uint_as_float(u << 16);
            float m0 = f0 + a * we[2 * p_] + bee[2 * p_];
            p[2 * p_] += m0 > 0.f ? m0 : 0.f;
            if (2 * p_ + 1 < N_FEAT) {
                float f1 = __uint_as_float(u & 0xffff0000u);
                float m1 = f1 + a * we[2 * p_ + 1] + bee[2 * p_ + 1];
                p[2 * p_ + 1] += m1 > 0.f ? m1 : 0.f;
            }
        }
    }
#pragma unroll
    for (int off = 8; off >= 1; off >>= 1)
#pragma unroll
        for (int k = 0; k < N_FEAT; ++k)
            p[k] += __shfl_xor(p[k], off, 16);
    if (l == 0) {
        uint4 sv = xp4[n];
#pragma unroll
        for (int k = 0; k < N_FEAT; ++k) {
            unsigned u = ((const unsigned*)&sv)[k >> 1];
            float fs = __uint_as_float((k & 1) ? (u & 0xffff0000u) : (u << 16));
            bf16 hb = __float2bfloat16(p[k] + fs);
            tl[m][k] = *(unsigned short*)&hb;
        }
    }
    __syncthreads();

    // MFMA node-update: one k-step (K=32, k>=7 are zeros)
    // Verified mapping (m89): A lane l: row=l&15, k=(l>>4)*8+q;
    //                         B lane l: col=l&15, k=(l>>4)*8+q;
    //                         D lane l: col=l&15, row=(l>>4)*4+reg.
    int c = lane & 15;
    int kq = lane >> 4;
    int jt0 = wave * 2, jt1 = jt0 + 1;
    f32x4 d0 = {0.f, 0.f, 0.f, 0.f}, d1 = {0.f, 0.f, 0.f, 0.f};
    const short8* wp = (const short8*)Wp1;
    short8 aF = *(const short8*)&tl[c][kq * 8];
    short8 b0 = wp[jt0 * 64 + lane];
    short8 b1 = wp[jt1 * 64 + lane];
    d0 = __builtin_amdgcn_mfma_f32_16x16x32_bf16(aF, b0, d0, 0, 0, 0);
    d1 = __builtin_amdgcn_mfma_f32_16x16x32_bf16(aF, b1, d1, 0, 0, 0);
    float bv0 = b[jt0 * 16 + c];
    float bv1 = b[jt1 * 16 + c];
#pragma unroll
    for (int i = 0; i < 4; ++i) {
        int mm = kq * 4 + i;
        size_t base = (size_t)(n0 + mm) * HID;
        float v0 = d0[i] + bv0;
        float v1 = d1[i] + bv1;
        hout8[base + jt0 * 16 + c] = enc8(v0 > 0.f ? v0 : 0.f);
        hout8[base + jt1 * 16 + c] = enc8(v1 > 0.f ? v1 : 0.f);
    }
}

// ---------------- Fused hidden layer: fp8 gather-aggregate + MFMA node-update ----------------
// Gather reads fp8 rows (128 B): halves fabric traffic + working set vs bf16.
// t stays bf16 in LDS; MFMA bf16 with fp32 accum. FP8OUT=1 -> fp8 output rows
// (feeds next gather); FP8OUT=0 -> bf16 output (feeds pooling).
// hout MUST differ from hin.
template<int FP8OUT>
__global__ __launch_bounds__(256) void hidden_layer(
        const unsigned char* __restrict__ hin8, const int2* __restrict__ csr,
        const int* __restrict__ rowptr, const float* __restrict__ We,
        const float* __restrict__ be, const bf16* __restrict__ Wp,
        const float* __restrict__ b, void* __restrict__ hout) {
    __shared__ __align__(16) unsigned short tl[NPB][TLP];   // bf16 bits, 4.3 KB
    int tid = threadIdx.x;
    int wave = tid >> 6;
    int lane = tid & 63;
    int el = lane >> 4;          // edge slot 0..3
    int fc = lane & 15;          // feature chunk: feats fc*8 .. fc*8+7
    int n0 = blockIdx.x * NPB;

    float we8[8], be8[8];
#pragma unroll
    for (int q = 0; q < 8; ++q) {
        we8[q] = We[fc * 8 + q];
        be8[q] = be[fc * 8 + q];
    }

    const uint2* hin2 = (const uint2*)hin8;   // one 128-feat fp8 row = 16 uint2

    for (int loc = 0; loc < 4; ++loc) {
        int m = wave * 4 + loc;
        int n = n0 + m;
        int r0 = rowptr[n], r1 = rowptr[n + 1];
        float acc[8];
#pragma unroll
        for (int q = 0; q < 8; ++q) acc[q] = 0.f;
#pragma unroll 2
        for (int i = r0 + el; i < r1; i += 4) {
            int2 sa = csr[i];
            float a = __int_as_float(sa.y);
            uint2 rv = hin2[(size_t)sa.x * 16 + fc];
#pragma unroll
            for (int q = 0; q < 4; ++q) {
                float f0 = dec8(rv.x, q);                    // feat fc*8+q
                float f1 = dec8(rv.y, q);                    // feat fc*8+4+q
                float m0 = f0 + a * we8[q] + be8[q];
                float m1 = f1 + a * we8[4 + q] + be8[4 + q];
                acc[q]     += m0 > 0.f ? m0 : 0.f;
                acc[4 + q] += m1 > 0.f ? m1 : 0.f;
            }
        }
        // combine the 4 edge slots (lanes l, l^16, l^32 share fc)
#pragma unroll
        for (int q = 0; q < 8; ++q) {
            acc[q] += __shfl_xor(acc[q], 16, 64);
            acc[q] += __shfl_xor(acc[q], 32, 64);
        }
        if (el == 0) {
            uint2 sv = hin2[(size_t)n * 16 + fc];
            unsigned short pk[8];
#pragma unroll
            for (int q = 0; q < 4; ++q) {
                float v0 = acc[q]     + dec8(sv.x, q);
                float v1 = acc[4 + q] + dec8(sv.y, q);
                bf16 h0 = __float2bfloat16(v0);
                bf16 h1 = __float2bfloat16(v1);
                pk[q]     = *(unsigned short*)&h0;
                pk[4 + q] = *(unsigned short*)&h1;
            }
            *(uint4*)&tl[m][fc * 8] = *(const uint4*)pk;   // one ds_write_b128
        }
    }
    __syncthreads();

    // MFMA node-update: out[m][j] = relu(b[j] + sum_k t[m][k] * W[k][j])
    // Verified mapping (m89): A lane l: row=l&15, k=(l>>4)*8+q;
    //                         B lane l: col=l&15, k=(l>>4)*8+q;
    //                         D lane l: col=l&15, row=(l>>4)*4+reg.
    int c = lane & 15;           // A row / D col
    int kq = lane >> 4;          // k-chunk selector
    int jt0 = wave * 2, jt1 = jt0 + 1;
    f32x4 d0 = {0.f, 0.f, 0.f, 0.f}, d1 = {0.f, 0.f, 0.f, 0.f};
    const short8* wp = (const short8*)Wp;
#pragma unroll
    for (int kk = 0; kk < 4; ++kk) {
        short8 a  = *(const short8*)&tl[c][kk * 32 + kq * 8];
        short8 b0 = wp[(jt0 * 4 + kk) * 64 + lane];
        short8 b1 = wp[(jt1 * 4 + kk) * 64 + lane];
        d0 = __builtin_amdgcn_mfma_f32_16x16x32_bf16(a, b0, d0, 0, 0, 0);
        d1 = __builtin_amdgcn_mfma_f32_16x16x32_bf16(a, b1, d1, 0, 0, 0);
    }
    float bv0 = b[jt0 * 16 + c];
    float bv1 = b[jt1 * 16 + c];
#pragma unroll
    for (int i = 0; i < 4; ++i) {
        int m = kq * 4 + i;
        size_t base = (size_t)(n0 + m) * HID;
        float v0 = d0[i] + bv0;
        float v1 = d1[i] + bv1;
        v0 = v0 > 0.f ? v0 : 0.f;
        v1 = v1 > 0.f ? v1 : 0.f;
        if (FP8OUT) {
            unsigned char* o8 = (unsigned char*)hout;
            o8[base + jt0 * 16 + c] = enc8(v0);
            o8[base + jt1 * 16 + c] = enc8(v1);
        } else {
            bf16* o16 = (bf16*)hout;
            o16[base + jt0 * 16 + c] = __float2bfloat16(v0);
            o16[base + jt1 * 16 + c] = __float2bfloat16(v1);
        }
    }
}

// ---------------- Pooling + head ----------------

__global__ void pool_kernel(const bf16* __restrict__ h, const int* __restrict__ batch,
                            float* __restrict__ pool, float* __restrict__ cnt) {
    int n0 = blockIdx.x * 64;
    int j = threadIdx.x;
    int nend = n0 + 64;
    if (nend > N_NODES) nend = N_NODES;
    if (n0 >= N_NODES) return;
    float sum = 0.f;
    int curg = batch[n0];
    int runstart = n0;
    for (int n = n0; n < nend; ++n) {
        int g = batch[n];
        if (g != curg) {
            atomicAdd(&pool[curg * HID + j], sum);
            if (j == 0) atomicAdd(&cnt[curg], (float)(n - runstart));
            sum = 0.f;
            curg = g;
            runstart = n;
        }
        sum += __bfloat162float(h[(size_t)n * HID + j]);
    }
    atomicAdd(&pool[curg * HID + j], sum);
    if (j == 0) atomicAdd(&cnt[curg], (float)(nend - runstart));
}

__global__ void final_kernel(const float* __restrict__ pool, const float* __restrict__ cnt,
                             const float* __restrict__ Wlin, const float* __restrict__ blin,
                             float* __restrict__ out) {
    int idx = threadIdx.x;
    if (idx >= N_GRAPHS * N_CLASS) return;
    int g = idx / N_CLASS, c = idx % N_CLASS;
    float invc = 1.f / fmaxf(cnt[g], 1.f);
    float acc = blin[c];
    for (int j = 0; j < HID; ++j) acc += pool[g * HID + j] * invc * Wlin[j * N_CLASS + c];
    out[idx] = acc;
}

extern "C" void kernel_launch(void* const* d_in, const int* in_sizes, int n_in,
                              void* d_out, int out_size, void* d_ws, size_t ws_size,
                              hipStream_t stream) {
    const float* x    = (const float*)d_in[0];
    const int*   ei   = (const int*)d_in[1];
    const float* ea   = (const float*)d_in[2];
    const int*   batch= (const int*)d_in[3];
    const float* We1  = (const float*)d_in[4];
    const float* be1  = (const float*)d_in[5];
    const float* W1   = (const float*)d_in[6];
    const float* b1   = (const float*)d_in[7];
    const float* We2  = (const float*)d_in[8];
    const float* be2  = (const float*)d_in[9];
    const float* W2   = (const float*)d_in[10];
    const float* b2   = (const float*)d_in[11];
    const float* We3  = (const float*)d_in[12];
    const float* be3  = (const float*)d_in[13];
    const float* W3   = (const float*)d_in[14];
    const float* b3   = (const float*)d_in[15];
    const float* Wlin = (const float*)d_in[16];
    const float* blin = (const float*)d_in[17];

    const int* src = ei;
    const int* dst = ei + N_EDGES;

    // workspace layout (csr first: 16B-aligned at base; all sizes 16B multiples)
    char* w = (char*)d_ws;
    int2*  csr    = (int2*)w;                    w += sizeof(int2) * (size_t)N_EDGES;   // 12.8 MB
    bf16*  Wp2    = (bf16*)w;                    w += sizeof(bf16) * 8 * 4 * 64 * 8;    // 32 KB
    bf16*  Wp3    = (bf16*)w;                    w += sizeof(bf16) * 8 * 4 * 64 * 8;    // 32 KB
    bf16*  Wp1    = (bf16*)w;                    w += sizeof(bf16) * 8 * 64 * 8;        // 8 KB
    bf16*  xp     = (bf16*)w;                    w += sizeof(bf16) * (size_t)N_NODES * 8; // 1.6 MB
    unsigned char* A8 = (unsigned char*)w;       w += (size_t)N_NODES * HID;            // 12.8 MB
    unsigned char* B8 = (unsigned char*)w;       w += (size_t)N_NODES * HID;            // 12.8 MB
    bf16*  A16    = (bf16*)w;                    w += sizeof(bf16) * (size_t)N_NODES * HID; // 25.6 MB
    float* pool   = (float*)w;                   w += sizeof(float) * N_GRAPHS * HID;
    float* cnt    = (float*)w;                   w += sizeof(float) * N_GRAPHS;
    int*   rowptr = (int*)w;                     w += sizeof(int) * (N_NODES + 1);
    int*   cursor = (int*)w;                     w += sizeof(int) * N_NODES;
    int*   deg    = (int*)w;                     w += sizeof(int) * N_NODES;
    int*   stmp   = (int*)w;                     w += sizeof(int) * N_NODES;
    int*   bsum   = (int*)w;                     w += sizeof(int) * SCAN_NBLK;
    int*   bcur   = (int*)w;                     w += sizeof(int) * NBKT;

    // Pass A/B temporaries alias A16 (25.6 MB >= 12.8 + 6.4); A16 is first
    // written by layer-3, strictly after scatter_local on the same stream.
    int2* tmp2 = (int2*)A16;
    int*  tmpd = (int*)((char*)A16 + sizeof(int2) * (size_t)N_EDGES);

    // ---- CSR build + weight/x pack ----
    hipMemsetAsync(deg, 0, sizeof(int) * N_NODES, stream);
    hipMemsetAsync(pool, 0, sizeof(float) * (N_GRAPHS * HID + N_GRAPHS), stream);
    hist_kernel<<<(N_EDGES + 255) / 256, 256, 0, stream>>>(dst, deg);
    pack_w<<<8, 256, 0, stream>>>(W2, Wp2);
    pack_w<<<8, 256, 0, stream>>>(W3, Wp3);
    pack_w1<<<2, 256, 0, stream>>>(W1, Wp1);
    pack_x<<<(N_NODES + 255) / 256, 256, 0, stream>>>(x, xp);
    scan_phase1<<<SCAN_NBLK, 1024, 0, stream>>>(deg, stmp, bsum);
    scan_phase2<<<1, 128, 0, stream>>>(bsum);
    scan_phase3<<<SCAN_NBLK, 1024, 0, stream>>>(stmp, bsum, rowptr, cursor, bcur);
    partition_kernel<<<(N_EDGES + TILE - 1) / TILE, 256, 0, stream>>>(src, dst, ea, bcur, tmp2, tmpd);
    scatter_local<<<8 * ((NBKT + 7) / 8) * CPB, 256, 0, stream>>>(tmp2, tmpd, rowptr, cursor, csr);

    // ---- Layer 1 (fused gather + MFMA) -> fp8 A8 ----
    layer1_fused<<<N_NODES / NPB, 256, 0, stream>>>(xp, csr, rowptr, We1, be1, Wp1, b1, A8);

    // ---- Layer 2: A8 -> B8 (fp8) ----
    hidden_layer<1><<<N_NODES / NPB, 256, 0, stream>>>(A8, csr, rowptr, We2, be2, Wp2, b2, (void*)B8);

    // ---- Layer 3: B8 -> A16 (bf16 for pooling) ----
    hidden_layer<0><<<N_NODES / NPB, 256, 0, stream>>>(B8, csr, rowptr, We3, be3, Wp3, b3, (void*)A16);

    // ---- Pool + head ----
    pool_kernel<<<(N_NODES + 63) / 64, HID, 0, stream>>>(A16, batch, pool, cnt);
    final_kernel<<<1, 64, 0, stream>>>(pool, cnt, Wlin, blin, (float*)d_out);
}

// Round 15
// 382.265 us; speedup vs baseline: 1.2798x; 1.2798x over previous
//
#include <hip/hip_runtime.h>
#include <hip/hip_bf16.h>

#define N_NODES 100000
#define N_EDGES 1600000
#define N_FEAT 7
#define HID 128
#define N_CLASS 5
#define N_GRAPHS 8
#define NPB 16  // nodes per block in fused layer kernels (grid 6250, 4 waves x 4 nodes)
#define TLP 136  // padded LDS row (bf16 elems): 272 B stride
#define TLP1 40  // layer-1 padded LDS row (K=32 zero-padded + 8)
#define NBKT 196       // ceil(N_NODES / 512) dst-buckets
#define BKT_SHIFT 9    // 512-node buckets
#define TILE 4096      // edges per partition block

typedef __hip_bfloat16 bf16;
typedef __attribute__((ext_vector_type(8))) short short8;   // 8 bf16 (4 VGPRs)
typedef __attribute__((ext_vector_type(4))) float f32x4;    // MFMA accumulator

// ---------------- CSR build v2 ----------------
// r11 conclusion: hidden_layer is a ~79us plateau (traffic halving changed
// nothing). Remaining ~320us is mid-tier + 17 dispatches. This build removes
// hist (1.6M scattered atomics), 3 scan kernels, and the cursor array:
// bucket_hist -> scan_buckets (1 block) -> partition -> bucket_sort
// (1 block per 512-node bucket: LDS hist+scan -> rowptr + L2-local scatter).

__global__ __launch_bounds__(256) void bucket_hist(const int* __restrict__ dst,
                                                   int* __restrict__ gcnt) {
    __shared__ int l[NBKT];
    int tid = threadIdx.x;
    for (int i = tid; i < NBKT; i += 256) l[i] = 0;
    __syncthreads();
    int e0 = blockIdx.x * TILE;
    int ne = N_EDGES - e0; if (ne > TILE) ne = TILE;
    for (int t = tid; t < ne; t += 256)
        atomicAdd(&l[dst[e0 + t] >> BKT_SHIFT], 1);
    __syncthreads();
    for (int i = tid; i < NBKT; i += 256)
        if (l[i]) atomicAdd(&gcnt[i], l[i]);
}

// 1 block: exclusive-scan bucket counts -> bstart/bcur; also zero pool+cnt,
// set rowptr[N].
__global__ __launch_bounds__(256) void scan_buckets(const int* __restrict__ gcnt,
                                                    int* __restrict__ bstart,
                                                    int* __restrict__ bcur,
                                                    int* __restrict__ rowptr,
                                                    float* __restrict__ pool) {
    __shared__ int s[256];
    int tid = threadIdx.x;
    int v = (tid < NBKT) ? gcnt[tid] : 0;
    s[tid] = v;
    __syncthreads();
    for (int o = 1; o < 256; o <<= 1) {
        int u = (tid >= o) ? s[tid - o] : 0;
        __syncthreads();
        s[tid] += u;
        __syncthreads();
    }
    if (tid < NBKT) { bstart[tid] = s[tid] - v; bcur[tid] = s[tid] - v; }
    if (tid == 0) rowptr[N_NODES] = N_EDGES;
    for (int i = tid; i < N_GRAPHS * HID + N_GRAPHS; i += 256) pool[i] = 0.f;
}

// Pass A: LDS counting-sort each edge tile by dst-bucket, write bucket-major.
__global__ __launch_bounds__(256) void partition_kernel(
        const int* __restrict__ src, const int* __restrict__ dst,
        const float* __restrict__ ea, int* __restrict__ bcur,
        int2* __restrict__ tmp2, int* __restrict__ tmpd) {
    __shared__ int lsrc[TILE], lea[TILE], ldst[TILE];   // 48 KB
    __shared__ int cnt[NBKT], gbase[NBKT];
    __shared__ int off[256];
    int tid = threadIdx.x;
    int e0 = blockIdx.x * TILE;
    int nedge = N_EDGES - e0; if (nedge > TILE) nedge = TILE;

    for (int bkt = tid; bkt < NBKT; bkt += 256) cnt[bkt] = 0;
    __syncthreads();
    for (int t = tid; t < nedge; t += 256)
        atomicAdd(&cnt[dst[e0 + t] >> BKT_SHIFT], 1);
    __syncthreads();
    off[tid] = (tid < NBKT) ? cnt[tid] : 0;
    __syncthreads();
    for (int o = 1; o < 256; o <<= 1) {                  // Hillis-Steele inclusive
        int u = (tid >= o) ? off[tid - o] : 0;
        __syncthreads();
        off[tid] += u;
        __syncthreads();
    }
    if (tid < NBKT) {
        off[tid] -= cnt[tid];                            // inclusive -> exclusive
        gbase[tid] = atomicAdd(&bcur[tid], cnt[tid]);    // reserve global bucket range
    }
    __syncthreads();
    if (tid < NBKT) cnt[tid] = 0;                        // reuse as rank counter
    __syncthreads();
    for (int t = tid; t < nedge; t += 256) {
        int d = dst[e0 + t];
        int bkt = d >> BKT_SHIFT;
        int sp = off[bkt] + atomicAdd(&cnt[bkt], 1);     // sorted slot in tile
        lsrc[sp] = src[e0 + t];
        lea[sp] = __float_as_int(ea[e0 + t]);
        ldst[sp] = d;
    }
    __syncthreads();
    for (int t = tid; t < nedge; t += 256) {             // bucket-grouped writeout
        int d = ldst[t];
        int bkt = d >> BKT_SHIFT;
        int gi = gbase[bkt] + (t - off[bkt]);
        tmp2[gi] = make_int2(lsrc[t], lea[t]);
        tmpd[gi] = d;
    }
}

// Pass B: one block per bucket. LDS per-node hist + scan -> rowptr segment;
// then scatter csr within the bucket's own ~100KB window (single block, single
// XCD -> L2-local, full-line write merging).
__global__ __launch_bounds__(512) void bucket_sort(
        const int2* __restrict__ tmp2, const int* __restrict__ tmpd,
        const int* __restrict__ bstart, const int* __restrict__ gcnt,
        int* __restrict__ rowptr, int2* __restrict__ csr) {
    __shared__ int s[512];
    __shared__ int lcur[512];
    int tid = threadIdx.x;
    int b = blockIdx.x;
    int nb0 = b << BKT_SHIFT;
    int r0 = bstart[b];
    int r1 = r0 + gcnt[b];
    s[tid] = 0;
    __syncthreads();
    for (int i = r0 + tid; i < r1; i += 512)
        atomicAdd(&s[tmpd[i] - nb0], 1);
    __syncthreads();
    int v = s[tid];
    for (int o = 1; o < 512; o <<= 1) {                  // inclusive scan
        int u = (tid >= o) ? s[tid - o] : 0;
        __syncthreads();
        s[tid] += u;
        __syncthreads();
    }
    int excl = s[tid] - v;
    lcur[tid] = excl;
    int n = nb0 + tid;
    if (n < N_NODES) rowptr[n] = r0 + excl;
    __syncthreads();
    for (int i = r0 + tid; i < r1; i += 512) {
        int d = tmpd[i];
        int p = r0 + atomicAdd(&lcur[d - nb0], 1);
        csr[p] = tmp2[i];
    }
}

// ---------------- merged pre-pack: Wp2, Wp3, Wp1, xp in one launch ----------------
// B-frag for mfma_f32_16x16x32_bf16: lane l holds B[k=(l>>4)*8+q][col=l&15].

__device__ __forceinline__ void pack_w_body(const float* W, bf16* Wp, int t) {
    int l = t & 63;
    int kk = (t >> 6) & 3;
    int jt = t >> 8;
    int kbase = kk * 32 + (l >> 4) * 8;
    int j = jt * 16 + (l & 15);
#pragma unroll
    for (int q = 0; q < 8; ++q)
        Wp[t * 8 + q] = __float2bfloat16(W[(kbase + q) * HID + j]);
}

__global__ __launch_bounds__(256) void pack_all(
        const float* __restrict__ W2, const float* __restrict__ W3,
        const float* __restrict__ W1, const float* __restrict__ x,
        bf16* __restrict__ Wp2, bf16* __restrict__ Wp3,
        bf16* __restrict__ Wp1, bf16* __restrict__ xp) {
    int bid = blockIdx.x, tid = threadIdx.x;
    if (bid < 8) {
        pack_w_body(W2, Wp2, bid * 256 + tid);
    } else if (bid < 16) {
        pack_w_body(W3, Wp3, (bid - 8) * 256 + tid);
    } else if (bid < 18) {
        int t = (bid - 16) * 256 + tid;          // 0..511: K=7 zero-padded to 32
        if (t < 512) {
            int l = t & 63;
            int jt = t >> 6;
            int j = jt * 16 + (l & 15);
#pragma unroll
            for (int q = 0; q < 8; ++q) {
                int k = (l >> 4) * 8 + q;
                Wp1[t * 8 + q] = __float2bfloat16(k < N_FEAT ? W1[k * HID + j] : 0.f);
            }
        }
    } else {
        int n = (bid - 18) * 256 + tid;          // x: fp32 [N][7] -> bf16 [N][8]
        if (n < N_NODES) {
            unsigned short pk[8];
#pragma unroll
            for (int k = 0; k < N_FEAT; ++k) {
                bf16 h = __float2bfloat16(x[n * N_FEAT + k]);
                pk[k] = *(unsigned short*)&h;
            }
            pk[7] = 0;
            *(uint4*)&xp[(size_t)n * 8] = *(const uint4*)pk;
        }
    }
}

// ---------------- Fused layer 1: gather(xp, in=7) + MFMA (r10 version) ----------------
__global__ __launch_bounds__(256) void layer1_fused(
        const bf16* __restrict__ xp, const int2* __restrict__ csr,
        const int* __restrict__ rowptr, const float* __restrict__ We,
        const float* __restrict__ be, const bf16* __restrict__ Wp1,
        const float* __restrict__ b, bf16* __restrict__ hout) {
    __shared__ __align__(16) unsigned short tl[NPB][TLP1];   // 1.28 KB
    int tid = threadIdx.x;
    int wave = tid >> 6;
    int lane = tid & 63;
    int sub = lane >> 4;
    int l = lane & 15;
    int n0 = blockIdx.x * NPB;

    for (int i = tid; i < NPB * TLP1; i += 256) ((unsigned short*)tl)[i] = 0;

    float we[N_FEAT], bee[N_FEAT], p[N_FEAT];
#pragma unroll
    for (int k = 0; k < N_FEAT; ++k) { we[k] = We[k]; bee[k] = be[k]; p[k] = 0.f; }
    __syncthreads();   // zero-init visible before lane-0 t-writes

    const uint4* xp4 = (const uint4*)xp;
    int m = wave * 4 + sub;
    int n = n0 + m;
    int r0 = rowptr[n], r1 = rowptr[n + 1];
    for (int i = r0 + l; i < r1; i += 16) {
        int2 sa = csr[i];
        float a = __int_as_float(sa.y);
        uint4 rv = xp4[sa.x];                        // whole 7-feat row, one load
#pragma unroll
        for (int p_ = 0; p_ < 4; ++p_) {
            unsigned u = ((const unsigned*)&rv)[p_];
            float f0 = __uint_as_float(u << 16);
            float m0 = f0 + a * we[2 * p_] + bee[2 * p_];
            p[2 * p_] += m0 > 0.f ? m0 : 0.f;
            if (2 * p_ + 1 < N_FEAT) {
                float f1 = __uint_as_float(u & 0xffff0000u);
                float m1 = f1 + a * we[2 * p_ + 1] + bee[2 * p_ + 1];
                p[2 * p_ + 1] += m1 > 0.f ? m1 : 0.f;
            }
        }
    }
#pragma unroll
    for (int off = 8; off >= 1; off >>= 1)
#pragma unroll
        for (int k = 0; k < N_FEAT; ++k)
            p[k] += __shfl_xor(p[k], off, 16);
    if (l == 0) {
        uint4 sv = xp4[n];
#pragma unroll
        for (int k = 0; k < N_FEAT; ++k) {
            unsigned u = ((const unsigned*)&sv)[k >> 1];
            float fs = __uint_as_float((k & 1) ? (u & 0xffff0000u) : (u << 16));
            bf16 hb = __float2bfloat16(p[k] + fs);
            tl[m][k] = *(unsigned short*)&hb;
        }
    }
    __syncthreads();

    // MFMA node-update: one k-step (K=32, k>=7 are zeros)
    // Verified mapping (m89): A lane l: row=l&15, k=(l>>4)*8+q;
    //                         B lane l: col=l&15, k=(l>>4)*8+q;
    //                         D lane l: col=l&15, row=(l>>4)*4+reg.
    int c = lane & 15;
    int kq = lane >> 4;
    int jt0 = wave * 2, jt1 = jt0 + 1;
    f32x4 d0 = {0.f, 0.f, 0.f, 0.f}, d1 = {0.f, 0.f, 0.f, 0.f};
    const short8* wp = (const short8*)Wp1;
    short8 aF = *(const short8*)&tl[c][kq * 8];
    short8 b0 = wp[jt0 * 64 + lane];
    short8 b1 = wp[jt1 * 64 + lane];
    d0 = __builtin_amdgcn_mfma_f32_16x16x32_bf16(aF, b0, d0, 0, 0, 0);
    d1 = __builtin_amdgcn_mfma_f32_16x16x32_bf16(aF, b1, d1, 0, 0, 0);
    float bv0 = b[jt0 * 16 + c];
    float bv1 = b[jt1 * 16 + c];
#pragma unroll
    for (int i = 0; i < 4; ++i) {
        int mm = kq * 4 + i;
        size_t base = (size_t)(n0 + mm) * HID;
        float v0 = d0[i] + bv0;
        float v1 = d1[i] + bv1;
        hout[base + jt0 * 16 + c] = __float2bfloat16(v0 > 0.f ? v0 : 0.f);
        hout[base + jt1 * 16 + c] = __float2bfloat16(v1 > 0.f ? v1 : 0.f);
    }
}

// ---------------- Fused hidden layer (r10 bf16 version — known 78.8us) ----------------
// hout MUST differ from hin.
__global__ __launch_bounds__(256) void hidden_layer(
        const bf16* __restrict__ hin, const int2* __restrict__ csr,
        const int* __restrict__ rowptr, const float* __restrict__ We,
        const float* __restrict__ be, const bf16* __restrict__ Wp,
        const float* __restrict__ b, bf16* __restrict__ hout) {
    __shared__ __align__(16) unsigned short tl[NPB][TLP];   // bf16 bits, 4.3 KB
    int tid = threadIdx.x;
    int wave = tid >> 6;
    int lane = tid & 63;
    int el = lane >> 4;          // edge slot 0..3
    int fc = lane & 15;          // feature chunk: feats fc*8 .. fc*8+7
    int n0 = blockIdx.x * NPB;

    float we8[8], be8[8];
#pragma unroll
    for (int q = 0; q < 8; ++q) {
        we8[q] = We[fc * 8 + q];
        be8[q] = be[fc * 8 + q];
    }

    const uint4* hin4 = (const uint4*)hin;   // one 128-feat bf16 row = 16 uint4

    for (int loc = 0; loc < 4; ++loc) {
        int m = wave * 4 + loc;
        int n = n0 + m;
        int r0 = rowptr[n], r1 = rowptr[n + 1];
        float acc[8];
#pragma unroll
        for (int q = 0; q < 8; ++q) acc[q] = 0.f;
#pragma unroll 2
        for (int i = r0 + el; i < r1; i += 4) {
            int2 sa = csr[i];
            int s = sa.x;
            float a = __int_as_float(sa.y);
            uint4 rv = hin4[(size_t)s * 16 + fc];
#pragma unroll
            for (int p = 0; p < 4; ++p) {
                unsigned u = ((const unsigned*)&rv)[p];
                float f0 = __uint_as_float(u << 16);          // low bf16
                float f1 = __uint_as_float(u & 0xffff0000u);  // high bf16
                float m0 = f0 + a * we8[2 * p] + be8[2 * p];
                float m1 = f1 + a * we8[2 * p + 1] + be8[2 * p + 1];
                acc[2 * p]     += m0 > 0.f ? m0 : 0.f;
                acc[2 * p + 1] += m1 > 0.f ? m1 : 0.f;
            }
        }
        // combine the 4 edge slots (lanes l, l^16, l^32 share fc)
#pragma unroll
        for (int q = 0; q < 8; ++q) {
            acc[q] += __shfl_xor(acc[q], 16, 64);
            acc[q] += __shfl_xor(acc[q], 32, 64);
        }
        if (el == 0) {
            uint4 sv = hin4[(size_t)n * 16 + fc];
            unsigned short pk[8];
#pragma unroll
            for (int p = 0; p < 4; ++p) {
                unsigned u = ((const unsigned*)&sv)[p];
                float v0 = acc[2 * p]     + __uint_as_float(u << 16);
                float v1 = acc[2 * p + 1] + __uint_as_float(u & 0xffff0000u);
                bf16 h0 = __float2bfloat16(v0);
                bf16 h1 = __float2bfloat16(v1);
                pk[2 * p]     = *(unsigned short*)&h0;
                pk[2 * p + 1] = *(unsigned short*)&h1;
            }
            *(uint4*)&tl[m][fc * 8] = *(const uint4*)pk;   // one ds_write_b128
        }
    }
    __syncthreads();

    // MFMA node-update: out[m][j] = relu(b[j] + sum_k t[m][k] * W[k][j])
    // Verified mapping (m89): A lane l: row=l&15, k=(l>>4)*8+q;
    //                         B lane l: col=l&15, k=(l>>4)*8+q;
    //                         D lane l: col=l&15, row=(l>>4)*4+reg.
    int c = lane & 15;           // A row / D col
    int kq = lane >> 4;          // k-chunk selector
    int jt0 = wave * 2, jt1 = jt0 + 1;
    f32x4 d0 = {0.f, 0.f, 0.f, 0.f}, d1 = {0.f, 0.f, 0.f, 0.f};
    const short8* wp = (const short8*)Wp;
#pragma unroll
    for (int kk = 0; kk < 4; ++kk) {
        short8 a  = *(const short8*)&tl[c][kk * 32 + kq * 8];
        short8 b0 = wp[(jt0 * 4 + kk) * 64 + lane];
        short8 b1 = wp[(jt1 * 4 + kk) * 64 + lane];
        d0 = __builtin_amdgcn_mfma_f32_16x16x32_bf16(a, b0, d0, 0, 0, 0);
        d1 = __builtin_amdgcn_mfma_f32_16x16x32_bf16(a, b1, d1, 0, 0, 0);
    }
    float bv0 = b[jt0 * 16 + c];
    float bv1 = b[jt1 * 16 + c];
#pragma unroll
    for (int i = 0; i < 4; ++i) {
        int m = kq * 4 + i;
        size_t base = (size_t)(n0 + m) * HID;
        float v0 = d0[i] + bv0;
        float v1 = d1[i] + bv1;
        hout[base + jt0 * 16 + c] = __float2bfloat16(v0 > 0.f ? v0 : 0.f);
        hout[base + jt1 * 16 + c] = __float2bfloat16(v1 > 0.f ? v1 : 0.f);
    }
}

// ---------------- Pooling + head ----------------

__global__ void pool_kernel(const bf16* __restrict__ h, const int* __restrict__ batch,
                            float* __restrict__ pool, float* __restrict__ cnt) {
    int n0 = blockIdx.x * 64;
    int j = threadIdx.x;
    int nend = n0 + 64;
    if (nend > N_NODES) nend = N_NODES;
    if (n0 >= N_NODES) return;
    float sum = 0.f;
    int curg = batch[n0];
    int runstart = n0;
    for (int n = n0; n < nend; ++n) {
        int g = batch[n];
        if (g != curg) {
            atomicAdd(&pool[curg * HID + j], sum);
            if (j == 0) atomicAdd(&cnt[curg], (float)(n - runstart));
            sum = 0.f;
            curg = g;
            runstart = n;
        }
        sum += __bfloat162float(h[(size_t)n * HID + j]);
    }
    atomicAdd(&pool[curg * HID + j], sum);
    if (j == 0) atomicAdd(&cnt[curg], (float)(nend - runstart));
}

__global__ void final_kernel(const float* __restrict__ pool, const float* __restrict__ cnt,
                             const float* __restrict__ Wlin, const float* __restrict__ blin,
                             float* __restrict__ out) {
    int idx = threadIdx.x;
    if (idx >= N_GRAPHS * N_CLASS) return;
    int g = idx / N_CLASS, c = idx % N_CLASS;
    float invc = 1.f / fmaxf(cnt[g], 1.f);
    float acc = blin[c];
    for (int j = 0; j < HID; ++j) acc += pool[g * HID + j] * invc * Wlin[j * N_CLASS + c];
    out[idx] = acc;
}

extern "C" void kernel_launch(void* const* d_in, const int* in_sizes, int n_in,
                              void* d_out, int out_size, void* d_ws, size_t ws_size,
                              hipStream_t stream) {
    const float* x    = (const float*)d_in[0];
    const int*   ei   = (const int*)d_in[1];
    const float* ea   = (const float*)d_in[2];
    const int*   batch= (const int*)d_in[3];
    const float* We1  = (const float*)d_in[4];
    const float* be1  = (const float*)d_in[5];
    const float* W1   = (const float*)d_in[6];
    const float* b1   = (const float*)d_in[7];
    const float* We2  = (const float*)d_in[8];
    const float* be2  = (const float*)d_in[9];
    const float* W2   = (const float*)d_in[10];
    const float* b2   = (const float*)d_in[11];
    const float* We3  = (const float*)d_in[12];
    const float* be3  = (const float*)d_in[13];
    const float* W3   = (const float*)d_in[14];
    const float* b3   = (const float*)d_in[15];
    const float* Wlin = (const float*)d_in[16];
    const float* blin = (const float*)d_in[17];

    const int* src = ei;
    const int* dst = ei + N_EDGES;

    // workspace layout (csr first: 16B-aligned at base)
    char* w = (char*)d_ws;
    int2*  csr    = (int2*)w;                    w += sizeof(int2) * (size_t)N_EDGES;   // 12.8 MB
    bf16*  Wp2    = (bf16*)w;                    w += sizeof(bf16) * 8 * 4 * 64 * 8;    // 32 KB
    bf16*  Wp3    = (bf16*)w;                    w += sizeof(bf16) * 8 * 4 * 64 * 8;    // 32 KB
    bf16*  Wp1    = (bf16*)w;                    w += sizeof(bf16) * 8 * 64 * 8;        // 8 KB
    bf16*  xp     = (bf16*)w;                    w += sizeof(bf16) * (size_t)N_NODES * 8; // 1.6 MB
    bf16*  A      = (bf16*)w;                    w += sizeof(bf16) * (size_t)N_NODES * HID; // 25.6 MB
    bf16*  B      = (bf16*)w;                    w += sizeof(bf16) * (size_t)N_NODES * HID; // 25.6 MB
    float* pool   = (float*)w;                   w += sizeof(float) * N_GRAPHS * HID;
    float* cnt    = (float*)w;                   w += sizeof(float) * N_GRAPHS;
    int*   rowptr = (int*)w;                     w += sizeof(int) * (N_NODES + 1);
    int*   gcnt   = (int*)w;                     w += sizeof(int) * NBKT;
    int*   bstart = (int*)w;                     w += sizeof(int) * NBKT;
    int*   bcur   = (int*)w;                     w += sizeof(int) * NBKT;

    // partition temporaries alias A (25.6 MB >= 12.8 + 6.4); A is first written
    // by layer1_fused, strictly after bucket_sort on the same stream.
    int2* tmp2 = (int2*)A;
    int*  tmpd = (int*)((char*)A + sizeof(int2) * (size_t)N_EDGES);

    // ---- CSR build v2 + packs (11 dispatches total) ----
    hipMemsetAsync(gcnt, 0, sizeof(int) * NBKT, stream);
    bucket_hist<<<(N_EDGES + TILE - 1) / TILE, 256, 0, stream>>>(dst, gcnt);
    pack_all<<<18 + (N_NODES + 255) / 256, 256, 0, stream>>>(W2, W3, W1, x, Wp2, Wp3, Wp1, xp);
    scan_buckets<<<1, 256, 0, stream>>>(gcnt, bstart, bcur, rowptr, pool);
    partition_kernel<<<(N_EDGES + TILE - 1) / TILE, 256, 0, stream>>>(src, dst, ea, bcur, tmp2, tmpd);
    bucket_sort<<<NBKT, 512, 0, stream>>>(tmp2, tmpd, bstart, gcnt, rowptr, csr);

    // ---- Layer 1 (fused gather + MFMA, packed x) ----
    layer1_fused<<<N_NODES / NPB, 256, 0, stream>>>(xp, csr, rowptr, We1, be1, Wp1, b1, A);

    // ---- Layer 2: A -> B ----
    hidden_layer<<<N_NODES / NPB, 256, 0, stream>>>(A, csr, rowptr, We2, be2, Wp2, b2, B);

    // ---- Layer 3: B -> A ----
    hidden_layer<<<N_NODES / NPB, 256, 0, stream>>>(B, csr, rowptr, We3, be3, Wp3, b3, A);

    // ---- Pool + head ----
    pool_kernel<<<(N_NODES + 63) / 64, HID, 0, stream>>>(A, batch, pool, cnt);
    final_kernel<<<1, 64, 0, stream>>>(pool, cnt, Wlin, blin, (float*)d_out);
}